// Round 13
// baseline (109.649 us; speedup 1.0000x reference)
//
#include <hip/hip_runtime.h>

typedef __bf16  bf16x8 __attribute__((ext_vector_type(8)));
typedef float   f32x4  __attribute__((ext_vector_type(4)));
typedef short   short8 __attribute__((ext_vector_type(8)));

static __device__ __forceinline__ unsigned short f2bf(float f) {
  union { float f; unsigned int u; } v; v.f = f;
  unsigned int u = v.u;
  u += 0x7fffu + ((u >> 16) & 1u);   // round-to-nearest-even
  return (unsigned short)(u >> 16);
}

// e2m1 decode: code = sign<<3 | e<<1 | m ; values {0,.5,1,1.5,2,3,4,6} * sign
static __device__ __forceinline__ float fp4_decode(int qc) {
  int e = (qc >> 1) & 3;
  float m = (float)(qc & 1);
  float mag = (e == 0) ? (0.5f * m)
                       : ((2.0f + m) * 0.5f * (float)(1 << (e - 1)));
  return (qc & 8) ? -mag : mag;
}

// Fused prep (R4-proven): blocks [0, nblkW/256) dequant W; rest convert x.
__global__ __launch_bounds__(256) void w4a16_prep(
    const int* __restrict__ wq, const float* __restrict__ wsc,
    short* __restrict__ wout, int nblkW,
    const float* __restrict__ x, short* __restrict__ xb, int n8) {
  const int nbW = nblkW >> 8;
  if ((int)blockIdx.x < nbW) {
    int idx = blockIdx.x * 256 + threadIdx.x;
    if (idx >= nblkW) return;
    float s = wsc[idx];
    const int4* qp = (const int4*)wq + (size_t)idx * 4;
    int4 q0 = qp[0], q1 = qp[1], q2 = qp[2], q3 = qp[3];
    short8 r0, r1;
    r0[0] = (short)f2bf(fp4_decode(q0.x) * s);
    r0[1] = (short)f2bf(fp4_decode(q0.y) * s);
    r0[2] = (short)f2bf(fp4_decode(q0.z) * s);
    r0[3] = (short)f2bf(fp4_decode(q0.w) * s);
    r0[4] = (short)f2bf(fp4_decode(q1.x) * s);
    r0[5] = (short)f2bf(fp4_decode(q1.y) * s);
    r0[6] = (short)f2bf(fp4_decode(q1.z) * s);
    r0[7] = (short)f2bf(fp4_decode(q1.w) * s);
    r1[0] = (short)f2bf(fp4_decode(q2.x) * s);
    r1[1] = (short)f2bf(fp4_decode(q2.y) * s);
    r1[2] = (short)f2bf(fp4_decode(q2.z) * s);
    r1[3] = (short)f2bf(fp4_decode(q2.w) * s);
    r1[4] = (short)f2bf(fp4_decode(q3.x) * s);
    r1[5] = (short)f2bf(fp4_decode(q3.y) * s);
    r1[6] = (short)f2bf(fp4_decode(q3.z) * s);
    r1[7] = (short)f2bf(fp4_decode(q3.w) * s);
    short8* op = (short8*)wout + (size_t)idx * 2;
    op[0] = r0;
    op[1] = r1;
  } else {
    int idx = (blockIdx.x - nbW) * 256 + threadIdx.x;
    if (idx >= n8) return;
    const float4* xp = (const float4*)x + (size_t)idx * 2;
    float4 a = xp[0], b = xp[1];
    short8 r;
    r[0] = (short)f2bf(a.x); r[1] = (short)f2bf(a.y);
    r[2] = (short)f2bf(a.z); r[3] = (short)f2bf(a.w);
    r[4] = (short)f2bf(b.x); r[5] = (short)f2bf(b.y);
    r[6] = (short)f2bf(b.z); r[7] = (short)f2bf(b.w);
    ((short8*)xb)[idx] = r;
  }
}

// ---------------------------------------------------------------------------
// C[M,N] = A[M,K] * B[N,K]^T, bf16 in, fp32 out.
// BM=128 x BN=256, BK=64, 8 waves (2x4), per-wave 64x64, 16x16x32 MFMA.
// DEFERRED-OPERAND pipeline (T3-min, properly instantiated):
//   iteration t: {vmcnt(0) [stage(t), issued last iter, landed] ->
//     raw s_barrier [publish tile t; no auto lgkm drain] ->
//     stage(t+1) [6 gload_lds] -> read A-frags(t)->set(t%2) ->
//     MFMA(t-1) half1 [lgkm(8) = prev-ops-done, ~free] ->
//     read B-frags(t)->set(t%2) -> MFMA(t-1) half2 [lgkm(15), ~free]}
//   This tile's 16 ds_reads have NO dependency with MFMA(t-1) -> the LDS
//   pipe services them entirely under the 1242-cyc MFMA block.
// NBUF=3: buffer rewritten at iter i was last read at iter i-2 (two
//   barriers of separation) — no read/write race.
// Swizzle (T2, R2-verified): 16B-chunk c XOR (row&7) on SOURCE and READ.
// ---------------------------------------------------------------------------
#define BM 128
#define BN 256
#define BK 64
#define NBUF 3
#define ASZ (BM * BK)          // 8192 shorts = 16KB
#define BSZ (BN * BK)          // 16384 shorts = 32KB

__global__ __launch_bounds__(512, 2) void w4a16_gemm_dp(
    const short* __restrict__ A, const short* __restrict__ B,
    float* __restrict__ C, int M, int N, int K) {
  __shared__ __attribute__((aligned(16))) short As[NBUF * ASZ];  // 48KB
  __shared__ __attribute__((aligned(16))) short Bs[NBUF * BSZ];  // 96KB

  const int tid  = threadIdx.x;
  const int lane = tid & 63;
  const int wid  = tid >> 6;      // 0..7
  const int wr   = wid >> 2;      // 0..1  (M)
  const int wc   = wid & 3;       // 0..3  (N)

  const int bm = blockIdx.y * BM;
  const int bn = blockIdx.x * BN;

  f32x4 acc[4][4] = {};           // [m-frag][n-frag]

  const int fr    = lane & 15;
  const int klane = lane >> 4;
  const int xv    = fr & 7;       // read-side swizzle XOR

  const size_t rowbytes = (size_t)K * 2;

  // ---- loop-invariant staging addresses (per-thread): only kt varies.
  size_t aoff[2];  int aldso[2];
#pragma unroll
  for (int r = 0; r < 2; ++r) {
    int u = r * 512 + tid;               // 0..1023
    int row = u >> 3, c = u & 7;
    int csrc = c ^ (row & 7);
    aoff[r]  = (size_t)(bm + row) * rowbytes + (size_t)csrc * 16;
    aldso[r] = u * 16;
  }
  size_t boff[4];  int bldso[4];
#pragma unroll
  for (int r = 0; r < 4; ++r) {
    int u = r * 512 + tid;               // 0..2047
    int row = u >> 3, c = u & 7;
    int csrc = c ^ (row & 7);
    boff[r]  = (size_t)(bn + row) * rowbytes + (size_t)csrc * 16;
    bldso[r] = u * 16;
  }

  const char* Ag = (const char*)A;
  const char* Bg = (const char*)B;

#define STAGE_A(bufbase, koff2, r)                                              \
  __builtin_amdgcn_global_load_lds(                                             \
      (const __attribute__((address_space(1))) unsigned int*)(Ag + aoff[r] + (koff2)), \
      (__attribute__((address_space(3))) unsigned int*)((char*)(bufbase) + aldso[r]),  \
      16, 0, 0)
#define STAGE_B(bufbase, koff2, r)                                              \
  __builtin_amdgcn_global_load_lds(                                             \
      (const __attribute__((address_space(1))) unsigned int*)(Bg + boff[r] + (koff2)), \
      (__attribute__((address_space(3))) unsigned int*)((char*)(bufbase) + bldso[r]),  \
      16, 0, 0)

  // swizzled fragment reads
  auto readA = [&](const short* Ab, int mi, int kk) -> bf16x8 {
    int row = wr * 64 + mi * 16 + fr;
    int c = kk * 4 + klane;
    return *(const bf16x8*)((const char*)Ab + (size_t)row * 128 + ((c ^ xv) << 4));
  };
  auto readB = [&](const short* Bb, int ni, int kk) -> bf16x8 {
    int row = wc * 64 + ni * 16 + fr;
    int c = kk * 4 + klane;
    return *(const bf16x8*)((const char*)Bb + (size_t)row * 128 + ((c ^ xv) << 4));
  };

  const int NT = K / BK;   // 64 (even)

  bf16x8 afA[4][2], bfA[4][2], afB[4][2], bfB[4][2];

  int cur = 0, nxt = 1;    // reads(i) <- buf cur; stage(i+1) -> buf nxt

  // ---- prologue: stage tile 0 into buf 0.
  {
    char* A0 = (char*)As; char* B0 = (char*)Bs;
    STAGE_A(A0, 0, 0); STAGE_A(A0, 0, 1);
    STAGE_B(B0, 0, 0); STAGE_B(B0, 0, 1); STAGE_B(B0, 0, 2); STAGE_B(B0, 0, 3);
  }

#define ITER(i_, RDA, RDB, MFA, MFB, DO_MFMA)                                   \
  do {                                                                          \
    asm volatile("s_waitcnt vmcnt(0)");   /* stage(i) landed (own slice) */     \
    __builtin_amdgcn_s_barrier();          /* publish tile i (raw, no drain) */ \
    if ((i_) + 1 < NT) {                                                        \
      char* An = (char*)(As + nxt * ASZ);                                       \
      char* Bn = (char*)(Bs + nxt * BSZ);                                       \
      const size_t ko_ = (size_t)((i_) + 1) * (BK * 2);                         \
      STAGE_A(An, ko_, 0); STAGE_A(An, ko_, 1);                                 \
      STAGE_B(Bn, ko_, 0); STAGE_B(Bn, ko_, 1);                                 \
      STAGE_B(Bn, ko_, 2); STAGE_B(Bn, ko_, 3);                                 \
    }                                                                           \
    __builtin_amdgcn_sched_barrier(0);                                          \
    {                                                                           \
      const short* Ac = As + cur * ASZ;                                         \
      _Pragma("unroll") for (int mi = 0; mi < 4; ++mi)                          \
        _Pragma("unroll") for (int kk = 0; kk < 2; ++kk)                        \
          RDA[mi][kk] = readA(Ac, mi, kk);                                      \
    }                                                                           \
    __builtin_amdgcn_sched_barrier(0);                                          \
    if (DO_MFMA) {                                                              \
      __builtin_amdgcn_s_setprio(1);                                            \
      _Pragma("unroll") for (int mi = 0; mi < 2; ++mi)                          \
        _Pragma("unroll") for (int ni = 0; ni < 4; ++ni)                        \
          _Pragma("unroll") for (int kk = 0; kk < 2; ++kk)                      \
            acc[mi][ni] = __builtin_amdgcn_mfma_f32_16x16x32_bf16(              \
                MFA[mi][kk], MFB[ni][kk], acc[mi][ni], 0, 0, 0);                \
      __builtin_amdgcn_s_setprio(0);                                            \
    }                                                                           \
    __builtin_amdgcn_sched_barrier(0);                                          \
    {                                                                           \
      const short* Bc = Bs + cur * BSZ;                                         \
      _Pragma("unroll") for (int ni = 0; ni < 4; ++ni)                          \
        _Pragma("unroll") for (int kk = 0; kk < 2; ++kk)                        \
          RDB[ni][kk] = readB(Bc, ni, kk);                                      \
    }                                                                           \
    __builtin_amdgcn_sched_barrier(0);                                          \
    if (DO_MFMA) {                                                              \
      __builtin_amdgcn_s_setprio(1);                                            \
      _Pragma("unroll") for (int mi = 2; mi < 4; ++mi)                          \
        _Pragma("unroll") for (int ni = 0; ni < 4; ++ni)                        \
          _Pragma("unroll") for (int kk = 0; kk < 2; ++kk)                      \
            acc[mi][ni] = __builtin_amdgcn_mfma_f32_16x16x32_bf16(              \
                MFA[mi][kk], MFB[ni][kk], acc[mi][ni], 0, 0, 0);                \
      __builtin_amdgcn_s_setprio(0);                                            \
    }                                                                           \
    cur = (cur == NBUF - 1) ? 0 : cur + 1;                                      \
    nxt = (nxt == NBUF - 1) ? 0 : nxt + 1;                                      \
  } while (0)

  // peel i=0 (no MFMA yet) and i=1 (first MFMA), then pairs.
  ITER(0, afA, bfA, afB, bfB, 0);
  ITER(1, afB, bfB, afA, bfA, 1);
  for (int t = 2; t < NT; t += 2) {
    ITER(t,     afA, bfA, afB, bfB, 1);
    ITER(t + 1, afB, bfB, afA, bfA, 1);
  }
  // final MFMA for tile NT-1 (odd -> regs in afB/bfB); compiler inserts lgkm.
  __builtin_amdgcn_s_setprio(1);
#pragma unroll
  for (int mi = 0; mi < 4; ++mi)
#pragma unroll
    for (int ni = 0; ni < 4; ++ni)
#pragma unroll
      for (int kk = 0; kk < 2; ++kk)
        acc[mi][ni] = __builtin_amdgcn_mfma_f32_16x16x32_bf16(
            afB[mi][kk], bfB[ni][kk], acc[mi][ni], 0, 0, 0);
  __builtin_amdgcn_s_setprio(0);

  // ---- epilogue: C/D map: col = lane&15, row = (lane>>4)*4 + reg
  const int cn = lane & 15;
  const int rb = (lane >> 4) * 4;
#pragma unroll
  for (int ai = 0; ai < 4; ++ai)
#pragma unroll
    for (int bj = 0; bj < 4; ++bj) {
      int m0 = bm + wr * 64 + ai * 16 + rb;
      int n0 = bn + wc * 64 + bj * 16 + cn;
#pragma unroll
      for (int r = 0; r < 4; ++r)
        C[(size_t)(m0 + r) * N + n0] = acc[ai][bj][r];
    }
}

extern "C" void kernel_launch(void* const* d_in, const int* in_sizes, int n_in,
                              void* d_out, int out_size, void* d_ws, size_t ws_size,
                              hipStream_t stream) {
  const float* x   = (const float*)d_in[0];
  const float* wsc = (const float*)d_in[1];
  const int*   wq  = (const int*)d_in[2];
  float* out = (float*)d_out;

  const int K = 4096;                 // in_features
  const int N = in_sizes[2] / K;      // out_features = 4096
  const int M = in_sizes[0] / K;      // batch*seq = 2048

  // workspace layout: W bf16 [N*K] then X bf16 [M*K]
  short* Wb = (short*)d_ws;
  short* Xb = Wb + (size_t)N * K;

  int nblkW = (N * K) / 16;           // 1048576
  int n8    = (M * K) / 8;            // 1048576
  int gridP = (nblkW >> 8) + ((n8 + 255) >> 8);
  w4a16_prep<<<gridP, 256, 0, stream>>>(wq, wsc, Wb, nblkW, x, Xb, n8);

  dim3 grid(N / BN, M / BM);
  w4a16_gemm_dp<<<grid, 512, 0, stream>>>(Xb, Wb, out, M, N, K);
}